// Round 16
// baseline (156.016 us; speedup 1.0000x reference)
//
#include <hip/hip_runtime.h>
#include <hip/hip_bf16.h>
#include <math.h>

// Problem constants
#define B_  16
#define N_  1024
#define E_  512
#define H_  8

typedef __attribute__((ext_vector_type(8)))  __bf16 bf16x8;
typedef __attribute__((ext_vector_type(4)))  float  f32x4;
typedef __attribute__((ext_vector_type(16))) float  f32x16;
typedef __attribute__((ext_vector_type(4)))  unsigned int u32x4;

struct alignas(16) bf8pack { __hip_bfloat16 v[8]; };
struct alignas(8)  bf4pack { __hip_bfloat16 v[4]; };

static __device__ __forceinline__ float bf2f(__hip_bfloat16 x) { return __bfloat162float(x); }
static __device__ __forceinline__ __hip_bfloat16 f2bf(float x) { return __float2bfloat16(x); }

static __device__ __forceinline__ unsigned pkbf(float lo, float hi) {
    unsigned r;
    asm("v_cvt_pk_bf16_f32 %0, %1, %2" : "=v"(r) : "v"(lo), "v"(hi));
    return r;
}
// v_permlane32_swap_b32 a, b:  a' = [a.lo32, b.lo32], b' = [a.hi32, b.hi32]
static __device__ __forceinline__ void swap32(unsigned &a, unsigned &b) {
    asm("v_permlane32_swap_b32 %0, %1" : "+v"(a), "+v"(b));
}
// async global->LDS, 16B per lane. LDS dest is wave-uniform base + lane*16.
static __device__ __forceinline__ void gload16(const __hip_bfloat16* g, __hip_bfloat16* l) {
    __builtin_amdgcn_global_load_lds(
        (const __attribute__((address_space(1))) unsigned*)g,
        (__attribute__((address_space(3))) unsigned*)l, 16, 0, 0);
}
#define MFMA32(a, b, c) __builtin_amdgcn_mfma_f32_32x32x16_bf16((a), (b), (c), 0, 0, 0)
#define MFMA16(a, b, c) __builtin_amdgcn_mfma_f32_16x16x32_bf16((a), (b), (c), 0, 0, 0)

// exact-grade GELU: erf via Abramowitz-Stegun 7.1.26 (|err| < 1.5e-7)
static __device__ __forceinline__ float gelu_f(float v) {
    float z = fabsf(v) * 0.70710678118654752f;
    float t = 1.0f / fmaf(0.3275911f, z, 1.0f);
    float p = t * fmaf(t, fmaf(t, fmaf(t, fmaf(t, 1.061405429f, -1.453152027f),
                                       1.421413741f), -0.284496736f), 0.254829592f);
    float e = __builtin_amdgcn_exp2f(-z * z * 1.4426950408889634f);
    float erf = 1.0f - p * e;
    erf = copysignf(erf, v);
    return 0.5f * v * (1.0f + erf);
}

// ---------------------------------------------------------------------------
// K0: merged prep + norm1.
// Blocks 0..127: LDS-tiled transpose W1,W2 -> bf16 [out][in].
// Blocks 128..135: per-head RBS orthogonal -> worth_t (SCL folded), Wv^T.
// Blocks 136..143: colsum1 (8 blocks x 64 cols, row-parallel + LDS reduce).
// Blocks 144..4239: LayerNorm(512) of x -> xn bf16 + raw bf16 copy -> xb.
// ---------------------------------------------------------------------------
__global__ __launch_bounds__(256) void k_prep(const float* __restrict__ phi,
                                              const float* __restrict__ Wv,
                                              const float* __restrict__ W1,
                                              const float* __restrict__ W2,
                                              const float* __restrict__ x,
                                              __hip_bfloat16* __restrict__ worth_t,
                                              __hip_bfloat16* __restrict__ wvt,
                                              __hip_bfloat16* __restrict__ w1t,
                                              __hip_bfloat16* __restrict__ w2t,
                                              float* __restrict__ csum1,
                                              __hip_bfloat16* __restrict__ xn,
                                              __hip_bfloat16* __restrict__ xb) {
    __shared__ float sh[64 * 65];
    int tid = threadIdx.x;
    if (blockIdx.x >= 144) {
        // ---- norm1 path: wave per row ----
        int w = tid >> 6, l = tid & 63;
        size_t row = (size_t)(blockIdx.x - 144) * 4 + w;
        const float* p = x + row * 512 + l * 8;
        float4 v0 = *reinterpret_cast<const float4*>(p);
        float4 v1 = *reinterpret_cast<const float4*>(p + 4);
        float vv[8] = {v0.x, v0.y, v0.z, v0.w, v1.x, v1.y, v1.z, v1.w};
        bf8pack xo;
#pragma unroll
        for (int j = 0; j < 8; ++j) xo.v[j] = f2bf(vv[j]);
        *reinterpret_cast<bf8pack*>(xb + row * 512 + l * 8) = xo;
        float s = 0.f, sq = 0.f;
#pragma unroll
        for (int j = 0; j < 8; ++j) { s += vv[j]; sq += vv[j] * vv[j]; }
#pragma unroll
        for (int o = 32; o >= 1; o >>= 1) { s += __shfl_xor(s, o); sq += __shfl_xor(sq, o); }
        float mean = s * (1.0f / 512.0f);
        float var  = sq * (1.0f / 512.0f) - mean * mean;
        float rstd = rsqrtf(var + 1e-5f);
        bf8pack ob;
#pragma unroll
        for (int j = 0; j < 8; ++j) ob.v[j] = f2bf((vv[j] - mean) * rstd);
        *reinterpret_cast<bf8pack*>(xn + row * 512 + l * 8) = ob;
    } else if (blockIdx.x < 128) {
        int bid = blockIdx.x;
        const float* src = (bid & 1) ? W2 : W1;
        __hip_bfloat16* dst = (bid & 1) ? w2t : w1t;
        int tile = bid >> 1;
        int i0 = (tile & 7) * 64, o0 = (tile >> 3) * 64;
        float (*ts)[65] = (float(*)[65])sh;
        int r = tid >> 4, c4 = (tid & 15) * 4;
#pragma unroll
        for (int j4 = 0; j4 < 4; ++j4) {
            float4 v = *reinterpret_cast<const float4*>(&src[(size_t)(i0 + r + 16 * j4) * 512 + o0 + c4]);
            ts[r + 16 * j4][c4 + 0] = v.x; ts[r + 16 * j4][c4 + 1] = v.y;
            ts[r + 16 * j4][c4 + 2] = v.z; ts[r + 16 * j4][c4 + 3] = v.w;
        }
        __syncthreads();
        int o = tid >> 3, cg = tid & 7;
#pragma unroll
        for (int half = 0; half < 2; ++half) {
            int oo = o + 32 * half;
            bf8pack p;
#pragma unroll
            for (int j = 0; j < 8; ++j) p.v[j] = f2bf(ts[cg * 8 + j][oo]);
            *reinterpret_cast<bf8pack*>(&dst[(size_t)(o0 + oo) * 512 + i0 + cg * 8]) = p;
        }
    } else if (blockIdx.x < 136) {
        const float SCL = 0.18033688011112042f;  // log2(e)/8, folds softmax scale
        int h = blockIdx.x - 128;
        int t = tid;  // column index e
        if (t < 64) {
            for (int i = 0; i < 64; ++i) sh[i * 65 + t] = (i == t) ? 1.0f : 0.0f;
            for (int g = 0; g < 125; ++g) {
                int k = (g < 63) ? g : (124 - g);
                float ph = phi[h * 125 + g];
                float c, s;
                __sincosf(ph, &s, &c);
                float a  = sh[k * 65 + t];
                float b  = sh[(k + 1) * 65 + t];
                sh[k * 65 + t]       =  c * a + s * b;
                sh[(k + 1) * 65 + t] = -s * a + c * b;
            }
            for (int d = 0; d < 64; ++d)
                worth_t[h * 4096 + t * 64 + d] = f2bf(sh[d * 65 + t] * SCL);
            for (int d = 0; d < 64; ++d)
                wvt[h * 4096 + t * 64 + d] = f2bf(Wv[h * 4096 + d * 64 + t]);
        }
    } else {
        // colsum1: block covers 64 cols; 16 row-groups x 32 rows in parallel.
        int c0 = (blockIdx.x - 136) * 64;
        float (*acc)[68] = (float(*)[68])sh;   // [16][64+pad]
        int cg = (tid & 15) * 4, rg = tid >> 4;
        float4 s4 = {0.f, 0.f, 0.f, 0.f};
        for (int rr = 0; rr < 32; ++rr) {
            float4 v = *reinterpret_cast<const float4*>(&W1[(size_t)(rg * 32 + rr) * 512 + c0 + cg]);
            s4.x += v.x; s4.y += v.y; s4.z += v.z; s4.w += v.w;
        }
        acc[rg][cg + 0] = s4.x; acc[rg][cg + 1] = s4.y;
        acc[rg][cg + 2] = s4.z; acc[rg][cg + 3] = s4.w;
        __syncthreads();
        if (tid < 64) {
            float s = 0.f;
#pragma unroll
            for (int g = 0; g < 16; ++g) s += acc[g][tid];
            csum1[c0 + tid] = s;
        }
    }
}

// ---------------------------------------------------------------------------
// K2: per-head projections via MFMA; outputs staged through padded LDS so all
// global stores are coalesced 16B.
// ---------------------------------------------------------------------------
__global__ __launch_bounds__(256) void k_proj(const __hip_bfloat16* __restrict__ xn,
                                              const __hip_bfloat16* __restrict__ worth_t,
                                              const __hip_bfloat16* __restrict__ wvt,
                                              const float* __restrict__ bv,
                                              __hip_bfloat16* __restrict__ xw,
                                              __hip_bfloat16* __restrict__ vt) {
    int h = blockIdx.y, rt = blockIdx.x;
    int tid = threadIdx.x, w = tid >> 6, l = tid & 63;
    int lr = l & 15, lg = l >> 4;
    int nw = rt * 64 + w * 16;
    int b  = (rt * 64) >> 10;
    int n0 = (rt * 64) & 1023;
    size_t bh = (size_t)b * H_ + h;

    __shared__ __hip_bfloat16 xw_l[64 * 72];  // [n][e], stride 72
    __shared__ __hip_bfloat16 vt_l[64 * 72];  // [e][n]

    const __hip_bfloat16* xp = xn + (size_t)(nw + lr) * 512 + h * 64 + lg * 8;
    bf16x8 xf0 = *reinterpret_cast<const bf16x8*>(xp);
    bf16x8 xf1 = *reinterpret_cast<const bf16x8*>(xp + 32);

    f32x4 accw[4] = {}, accv[4] = {};
#pragma unroll
    for (int g = 0; g < 4; ++g) {
        const __hip_bfloat16* wp = worth_t + h * 4096 + (g * 16 + lr) * 64 + lg * 8;
        accw[g] = MFMA16(*reinterpret_cast<const bf16x8*>(wp), xf0, accw[g]);
        accw[g] = MFMA16(*reinterpret_cast<const bf16x8*>(wp + 32), xf1, accw[g]);
        const __hip_bfloat16* vp = wvt + h * 4096 + (g * 16 + lr) * 64 + lg * 8;
        accv[g] = MFMA16(xf0, *reinterpret_cast<const bf16x8*>(vp), accv[g]);
        accv[g] = MFMA16(xf1, *reinterpret_cast<const bf16x8*>(vp + 32), accv[g]);
    }
#pragma unroll
    for (int g = 0; g < 4; ++g) {
        bf4pack pw;
#pragma unroll
        for (int r = 0; r < 4; ++r) pw.v[r] = f2bf(accw[g][r]);
        *reinterpret_cast<bf4pack*>(&xw_l[(w * 16 + lr) * 72 + g * 16 + lg * 4]) = pw;
        float bb = bv[h * 64 + g * 16 + lr];
        bf4pack pv;
#pragma unroll
        for (int r = 0; r < 4; ++r) pv.v[r] = f2bf(accv[g][r] + bb);
        *reinterpret_cast<bf4pack*>(&vt_l[(g * 16 + lr) * 72 + w * 16 + lg * 4]) = pv;
    }
    __syncthreads();
    {
        int rr = tid >> 2, c0 = (tid & 3) * 16;
        bf8pack p0 = *reinterpret_cast<const bf8pack*>(&xw_l[rr * 72 + c0]);
        bf8pack p1 = *reinterpret_cast<const bf8pack*>(&xw_l[rr * 72 + c0 + 8]);
        __hip_bfloat16* d1 = xw + (bh * N_ + n0 + rr) * 64 + c0;
        *reinterpret_cast<bf8pack*>(d1)     = p0;
        *reinterpret_cast<bf8pack*>(d1 + 8) = p1;
        bf8pack q0 = *reinterpret_cast<const bf8pack*>(&vt_l[rr * 72 + c0]);
        bf8pack q1 = *reinterpret_cast<const bf8pack*>(&vt_l[rr * 72 + c0 + 8]);
        __hip_bfloat16* d2 = vt + (bh * 64 + rr) * N_ + n0 + c0;
        *reinterpret_cast<bf8pack*>(d2)     = q0;
        *reinterpret_cast<bf8pack*>(d2 + 8) = q1;
    }
}

// ---------------------------------------------------------------------------
// K3: attention (r8/r13 structure, best measured). 8 waves, QBLK=256,
// KVBLK=128, double-buffered LDS. Swapped QK^T 32x32x16, lane-local softmax
// (no max), setprio around MFMA clusters. Epilogue: per-head LN(attn+xh)+xb.
// ---------------------------------------------------------------------------
__global__ __launch_bounds__(512, 4) void k_attn(const __hip_bfloat16* __restrict__ xn,
                                                 const __hip_bfloat16* __restrict__ xw,
                                                 const __hip_bfloat16* __restrict__ vt,
                                                 const __hip_bfloat16* __restrict__ xb,
                                                 __hip_bfloat16* __restrict__ res) {
    int h = blockIdx.x, b = blockIdx.z;
    int tid = threadIdx.x;
    int w = tid >> 6, l = tid & 63;
    int lq = l & 31, hi = l >> 5;
    int q0 = blockIdx.y * 256 + w * 32;
    size_t bh = (size_t)b * H_ + h;

    __shared__ __hip_bfloat16 kb[2][128 * 64];  // [kv 128][d 64]
    __shared__ __hip_bfloat16 vb[2][64 * 128];  // [d 64][kv 128]
    __shared__ float lred[8][32];

    int krow = w * 16 + (l >> 3);
    const __hip_bfloat16* ksrc = xn + ((size_t)b * N_ + krow) * 512 + h * 64
                               + (((l & 7) ^ (krow & 7)) << 3);
    int vrow0 = w * 8 + (l >> 4);
    int vrow1 = vrow0 + 4;
    const __hip_bfloat16* vsrc0 = vt + (bh * 64 + vrow0) * N_ + (((l & 15) ^ (vrow0 & 15)) << 3);
    const __hip_bfloat16* vsrc1 = vt + (bh * 64 + vrow1) * N_ + (((l & 15) ^ (vrow1 & 15)) << 3);

#define STAGE(t) do { int bf_ = (t) & 1; \
        gload16(ksrc + (size_t)((t) * 128) * 512,     &kb[bf_][(w * 16) * 64]); \
        gload16(ksrc + (size_t)((t) * 128 + 8) * 512, &kb[bf_][(w * 16 + 8) * 64]); \
        gload16(vsrc0 + (t) * 128, &vb[bf_][(w * 8) * 128]); \
        gload16(vsrc1 + (t) * 128, &vb[bf_][(w * 8 + 4) * 128]); } while (0)
#define TILE_BAR() do { \
        asm volatile("s_waitcnt vmcnt(0)" ::: "memory"); \
        __builtin_amdgcn_s_barrier(); \
        __builtin_amdgcn_sched_barrier(0); } while (0)

    const __hip_bfloat16* qp = xw + (bh * N_ + q0 + lq) * 64 + 8 * hi;
    bf16x8 qf0 = *reinterpret_cast<const bf16x8*>(qp);
    bf16x8 qf1 = *reinterpret_cast<const bf16x8*>(qp + 16);
    bf16x8 qf2 = *reinterpret_cast<const bf16x8*>(qp + 32);
    bf16x8 qf3 = *reinterpret_cast<const bf16x8*>(qp + 48);

    f32x16 o0 = {}, o1 = {};
    float l_run = 0.f;
    int kso = lq & 7;
    int vso = lq & 15;

    auto body = [&](int bf_, int mm) {
        const __hip_bfloat16* kc = &kb[bf_][mm * 64 * 64];
        const __hip_bfloat16* vc = &vb[bf_][0];
        f32x16 s0 = {}, s1 = {};
        __builtin_amdgcn_s_setprio(1);
#pragma unroll
        for (int kd = 0; kd < 4; ++kd) {
            bf16x8 qf = (kd == 0) ? qf0 : (kd == 1) ? qf1 : (kd == 2) ? qf2 : qf3;
            int sl = ((kd * 2 + hi) ^ kso) << 3;
            bf16x8 ka0 = *reinterpret_cast<const bf16x8*>(kc + lq * 64 + sl);
            bf16x8 ka1 = *reinterpret_cast<const bf16x8*>(kc + (lq + 32) * 64 + sl);
            s0 = MFMA32(ka0, qf, s0);
            s1 = MFMA32(ka1, qf, s1);
        }
        __builtin_amdgcn_s_setprio(0);
#pragma unroll
        for (int i = 0; i < 16; ++i) {
            s0[i] = __builtin_amdgcn_exp2f(s0[i]);
            s1[i] = __builtin_amdgcn_exp2f(s1[i]);
        }
        float ls = 0.f;
#pragma unroll
        for (int i = 0; i < 16; ++i) ls += s0[i] + s1[i];
        l_run += ls;
        bf16x8 pa[4];
        {
            unsigned u0 = pkbf(s0[0], s0[1]), u1 = pkbf(s0[2], s0[3]);
            unsigned u2 = pkbf(s0[4], s0[5]), u3 = pkbf(s0[6], s0[7]);
            swap32(u0, u2); swap32(u1, u3);
            u32x4 uu = {u0, u1, u2, u3};
            pa[0] = __builtin_bit_cast(bf16x8, uu);
        }
        {
            unsigned u0 = pkbf(s0[8], s0[9]),   u1 = pkbf(s0[10], s0[11]);
            unsigned u2 = pkbf(s0[12], s0[13]), u3 = pkbf(s0[14], s0[15]);
            swap32(u0, u2); swap32(u1, u3);
            u32x4 uu = {u0, u1, u2, u3};
            pa[1] = __builtin_bit_cast(bf16x8, uu);
        }
        {
            unsigned u0 = pkbf(s1[0], s1[1]), u1 = pkbf(s1[2], s1[3]);
            unsigned u2 = pkbf(s1[4], s1[5]), u3 = pkbf(s1[6], s1[7]);
            swap32(u0, u2); swap32(u1, u3);
            u32x4 uu = {u0, u1, u2, u3};
            pa[2] = __builtin_bit_cast(bf16x8, uu);
        }
        {
            unsigned u0 = pkbf(s1[8], s1[9]),   u1 = pkbf(s1[10], s1[11]);
            unsigned u2 = pkbf(s1[12], s1[13]), u3 = pkbf(s1[14], s1[15]);
            swap32(u0, u2); swap32(u1, u3);
            u32x4 uu = {u0, u1, u2, u3};
            pa[3] = __builtin_bit_cast(bf16x8, uu);
        }
        __builtin_amdgcn_s_setprio(1);
#pragma unroll
        for (int ks = 0; ks < 4; ++ks) {
            int sl = ((mm * 8 + ks * 2 + hi) ^ vso) << 3;
            bf16x8 v0 = *reinterpret_cast<const bf16x8*>(vc + lq * 128 + sl);
            bf16x8 v1 = *reinterpret_cast<const bf16x8*>(vc + (lq + 32) * 128 + sl);
            o0 = MFMA32(pa[ks], v0, o0);
            o1 = MFMA32(pa[ks], v1, o1);
        }
        __builtin_amdgcn_s_setprio(0);
    };

    STAGE(0);
    TILE_BAR();
    for (int t = 0; t < 7; ++t) {
        STAGE(t + 1);
        body(t & 1, 0);
        body(t & 1, 1);
        TILE_BAR();
    }
    body(1, 0);
    body(1, 1);

    // ---- finalize: per-head LN(attn + xh) + xb -> res (bf16) ----
    float lt = l_run + __shfl_xor(l_run, 32);
    if (hi == 0) lred[w][lq] = 1.0f / lt;
#pragma unroll
    for (int r = 0; r < 16; ++r) {
        int qr = (r & 3) + 8 * (r >> 2) + 4 * hi;
        float li = lred[w][qr];
        size_t base = ((size_t)b * N_ + q0 + qr) * 512 + h * 64;
        float t0 = o0[r] * li + bf2f(xn[base + lq]);
        float t1 = o1[r] * li + bf2f(xn[base + 32 + lq]);
        float s1v = t0 + t1, s2v = t0 * t0 + t1 * t1;
#pragma unroll
        for (int off = 16; off >= 1; off >>= 1) { s1v += __shfl_xor(s1v, off); s2v += __shfl_xor(s2v, off); }
        float mean = s1v * (1.0f / 64.0f);
        float var  = s2v * (1.0f / 64.0f) - mean * mean;
        float rstd = rsqrtf(var + 1e-5f);
        res[base + lq]      = f2bf((t0 - mean) * rstd + bf2f(xb[base + lq]));
        res[base + 32 + lq] = f2bf((t1 - mean) * rstd + bf2f(xb[base + 32 + lq]));
    }
#undef STAGE
#undef TILE_BAR
}

// ---------------------------------------------------------------------------
// K5/K6: GEMM 16384x512x512, bf16 MFMA (r10 structure, proven). Block =
// 128x64 tile, 4 waves x 32 rows. Bt panel staged in k-chunks of 128
// (2 x 16 KB LDS, double-buffered). Grid (rt=128, ct=8): XCD = rt%8.
// MODE 0: LN stats computed in a TRANSIENT prologue (before acc init, all
//         temporaries dead by MFMA loop; carried state = 2 VGPRs: lane l&31
//         holds row w*32+(l&31)'s {rstd, mean*rstd}), routed via __shfl in
//         the epilogue. out = gelu(acc*rstd + b1 - mean*rstd*csum) -> bf16.
// MODE 1: out = A@Bt^T + bias + res -> f32.
// ---------------------------------------------------------------------------
template <int MODE>
__global__ __launch_bounds__(256, 5) void k_gemm(const __hip_bfloat16* __restrict__ A,
                                                 const __hip_bfloat16* __restrict__ Bt,
                                                 const float* __restrict__ bias,
                                                 const __hip_bfloat16* __restrict__ resid,
                                                 const float* __restrict__ csum,
                                                 __hip_bfloat16* __restrict__ outb,
                                                 float* __restrict__ outf) {
    int m0 = blockIdx.x * 128, nn0 = blockIdx.y * 64;
    int tid = threadIdx.x, w = tid >> 6, l = tid & 63;
    int lr = l & 15, lg = l >> 4;
    __shared__ __hip_bfloat16 bs[2][64 * 128];  // 32 KB total

    int srow = w * 16 + (l >> 4);
    int sslot = l & 15;

#define GSTAGE(c) do { \
        _Pragma("unroll") \
        for (int i_ = 0; i_ < 4; ++i_) { \
            int row_ = srow + i_ * 4; \
            gload16(Bt + (size_t)(nn0 + row_) * 512 + (c) * 128 + ((sslot ^ (row_ & 15)) << 3), \
                    &bs[(c) & 1][(w * 16 + i_ * 4) * 128]); \
        } } while (0)

    GSTAGE(0);

    // ---- transient LN-stat prologue (MODE 0): wave w covers rows w*32..+31 ----
    float rstd_reg = 0.f, mr_reg = 0.f;
    if constexpr (MODE == 0) {
#pragma unroll 4
        for (int i = 0; i < 32; ++i) {
            bf16x8 u = *reinterpret_cast<const bf16x8*>(
                A + (size_t)(m0 + w * 32 + i) * 512 + l * 8);
            float s = 0.f, sq = 0.f;
#pragma unroll
            for (int j = 0; j < 8; ++j) { float a = (float)u[j]; s += a; sq = fmaf(a, a, sq); }
#pragma unroll
            for (int o = 32; o >= 1; o >>= 1) { s += __shfl_xor(s, o); sq += __shfl_xor(sq, o); }
            float mean = s * (1.0f / 512.0f);
            float var  = sq * (1.0f / 512.0f) - mean * mean;
            float rstd = rsqrtf(var + 1e-5f);
            if ((l & 31) == i) { rstd_reg = rstd; mr_reg = mean * rstd; }
        }
    }

    asm volatile("s_waitcnt vmcnt(0)" ::: "memory");
    __builtin_amdgcn_s_barrier();
    __builtin_amdgcn_sched_barrier(0);

    f32x4 acc0[4] = {}, acc1[4] = {};
    const __hip_bfloat16* ap0 = A + (size_t)(m0 + w * 32 + lr) * 512 + lg * 8;
    const __hip_bfloat16* ap1 = ap0 + 16 * 512;
#pragma unroll
    for (int c = 0; c < 4; ++c) {
        if (c < 3) GSTAGE(c + 1);
        const __hip_bfloat16* bc = &bs[c & 1][0];
#pragma unroll
        for (int kk = 0; kk < 4; ++kk) {
            bf16x8 a0 = *reinterpret_cast<const bf16x8*>(ap0 + c * 128 + kk * 32);
            bf16x8 a1 = *reinterpret_cast<const bf16x8*>(ap1 + c * 128 + kk * 32);
#pragma unroll
            for (int g = 0; g < 4; ++g) {
                int row = g * 16 + lr;
                bf16x8 bf = *reinterpret_cast<const bf16x8*>(
                    bc + row * 128 + (((kk * 4 + lg) ^ (row & 15)) << 3));
                acc0[g] = MFMA16(a0, bf, acc0[g]);
                acc1[g] = MFMA16(a1, bf, acc1[g]);
            }
        }
        if (c < 3) {
            asm volatile("s_waitcnt vmcnt(0)" ::: "memory");
            __builtin_amdgcn_s_barrier();
            __builtin_amdgcn_sched_barrier(0);
        }
    }
#undef GSTAGE
#pragma unroll
    for (int g = 0; g < 4; ++g) {
        int col = nn0 + g * 16 + lr;
        float bb = bias[col];
        float cc = (MODE == 0) ? csum[col] : 0.f;
#pragma unroll
        for (int r = 0; r < 4; ++r) {
            int row0 = m0 + w * 32 + lg * 4 + r;
            if (MODE == 0) {
                // row w*32+(lg*4+r) stats live in lane lg*4+r; +16 in lane lg*4+r+16
                float rs0 = __shfl(rstd_reg, lg * 4 + r);
                float mr0 = __shfl(mr_reg,  lg * 4 + r);
                float rs1 = __shfl(rstd_reg, lg * 4 + r + 16);
                float mr1 = __shfl(mr_reg,  lg * 4 + r + 16);
                float v0 = fmaf(acc0[g][r], rs0, fmaf(-mr0, cc, bb));
                float v1 = fmaf(acc1[g][r], rs1, fmaf(-mr1, cc, bb));
                outb[(size_t)row0 * 512 + col] = f2bf(gelu_f(v0));
                outb[(size_t)(row0 + 16) * 512 + col] = f2bf(gelu_f(v1));
            } else {
                size_t i0 = (size_t)row0 * 512 + col;
                size_t i1 = (size_t)(row0 + 16) * 512 + col;
                outf[i0] = acc0[g][r] + bb + bf2f(resid[i0]);
                outf[i1] = acc1[g][r] + bb + bf2f(resid[i1]);
            }
        }
    }
}

// ---------------------------------------------------------------------------
extern "C" void kernel_launch(void* const* d_in, const int* in_sizes, int n_in,
                              void* d_out, int out_size, void* d_ws, size_t ws_size,
                              hipStream_t stream) {
    const float* x   = (const float*)d_in[0];
    const float* Wv  = (const float*)d_in[1];
    const float* bv  = (const float*)d_in[2];
    const float* phi = (const float*)d_in[3];
    const float* W1  = (const float*)d_in[4];
    const float* b1  = (const float*)d_in[5];
    const float* W2  = (const float*)d_in[6];
    const float* b2  = (const float*)d_in[7];
    float* out = (float*)d_out;

    char* ws = (char*)d_ws;
    __hip_bfloat16* worth_t = (__hip_bfloat16*)(ws + 0);          // 64 KB
    __hip_bfloat16* wvt     = (__hip_bfloat16*)(ws + 65536);      // 64 KB
    __hip_bfloat16* w1t     = (__hip_bfloat16*)(ws + 131072);     // 512 KB
    __hip_bfloat16* w2t     = (__hip_bfloat16*)(ws + 655360);     // 512 KB
    float*          csum1   = (float*)(ws + 1179648);             // 2 KB
    __hip_bfloat16* xn      = (__hip_bfloat16*)(ws + 1312768);    // 16 MB
    __hip_bfloat16* xw      = (__hip_bfloat16*)(ws + 18089984);   // 16 MB
    __hip_bfloat16* vt      = (__hip_bfloat16*)(ws + 34867200);   // 16 MB
    __hip_bfloat16* res     = (__hip_bfloat16*)(ws + 51644416);   // 16 MB
    __hip_bfloat16* y1      = (__hip_bfloat16*)(ws + 68421632);   // 16 MB
    __hip_bfloat16* xb      = (__hip_bfloat16*)(ws + 85198848);   // 16 MB

    k_prep<<<dim3(4240), dim3(256), 0, stream>>>(phi, Wv, W1, W2, x,
                                                 worth_t, wvt, w1t, w2t, csum1, xn, xb);
    k_proj<<<dim3(256, 8), dim3(256), 0, stream>>>(xn, worth_t, wvt, bv, xw, vt);
    k_attn<<<dim3(8, 4, 16), dim3(512), 0, stream>>>(xn, xw, vt, xb, res);
    k_gemm<0><<<dim3(128, 8), dim3(256), 0, stream>>>(res, w1t, b1, nullptr, csum1, y1, nullptr);
    k_gemm<1><<<dim3(128, 8), dim3(256), 0, stream>>>(y1, w2t, b2, res, nullptr, nullptr, out);
}

// Round 17
// 146.987 us; speedup vs baseline: 1.0614x; 1.0614x over previous
//
#include <hip/hip_runtime.h>
#include <hip/hip_bf16.h>
#include <math.h>

// Problem constants
#define B_  16
#define N_  1024
#define E_  512
#define H_  8

typedef __attribute__((ext_vector_type(8)))  __bf16 bf16x8;
typedef __attribute__((ext_vector_type(4)))  float  f32x4;
typedef __attribute__((ext_vector_type(16))) float  f32x16;
typedef __attribute__((ext_vector_type(4)))  unsigned int u32x4;

struct alignas(16) bf8pack { __hip_bfloat16 v[8]; };
struct alignas(8)  bf4pack { __hip_bfloat16 v[4]; };

static __device__ __forceinline__ float bf2f(__hip_bfloat16 x) { return __bfloat162float(x); }
static __device__ __forceinline__ __hip_bfloat16 f2bf(float x) { return __float2bfloat16(x); }

static __device__ __forceinline__ unsigned pkbf(float lo, float hi) {
    unsigned r;
    asm("v_cvt_pk_bf16_f32 %0, %1, %2" : "=v"(r) : "v"(lo), "v"(hi));
    return r;
}
// v_permlane32_swap_b32 a, b:  a' = [a.lo32, b.lo32], b' = [a.hi32, b.hi32]
static __device__ __forceinline__ void swap32(unsigned &a, unsigned &b) {
    asm("v_permlane32_swap_b32 %0, %1" : "+v"(a), "+v"(b));
}
// async global->LDS, 16B per lane. LDS dest is wave-uniform base + lane*16.
static __device__ __forceinline__ void gload16(const __hip_bfloat16* g, __hip_bfloat16* l) {
    __builtin_amdgcn_global_load_lds(
        (const __attribute__((address_space(1))) unsigned*)g,
        (__attribute__((address_space(3))) unsigned*)l, 16, 0, 0);
}
#define MFMA32(a, b, c) __builtin_amdgcn_mfma_f32_32x32x16_bf16((a), (b), (c), 0, 0, 0)
#define MFMA16(a, b, c) __builtin_amdgcn_mfma_f32_16x16x32_bf16((a), (b), (c), 0, 0, 0)

// C(32x32)->frag repack (proven in P->pa path): input 8 f32 (C regs r: idx
// (r&3)+8*(r>>2)+4*hi), output bf16x8 frag elem j at idx 8*hi+j (A/B layout).
#define PACK8(dst, s, base) do { \
        unsigned u0 = pkbf((s)[(base)+0], (s)[(base)+1]), u1 = pkbf((s)[(base)+2], (s)[(base)+3]); \
        unsigned u2 = pkbf((s)[(base)+4], (s)[(base)+5]), u3 = pkbf((s)[(base)+6], (s)[(base)+7]); \
        swap32(u0, u2); swap32(u1, u3); \
        u32x4 uu = {u0, u1, u2, u3}; \
        dst = __builtin_bit_cast(bf16x8, uu); } while (0)

// exact-grade GELU: erf via Abramowitz-Stegun 7.1.26 (|err| < 1.5e-7)
static __device__ __forceinline__ float gelu_f(float v) {
    float z = fabsf(v) * 0.70710678118654752f;
    float t = 1.0f / fmaf(0.3275911f, z, 1.0f);
    float p = t * fmaf(t, fmaf(t, fmaf(t, fmaf(t, 1.061405429f, -1.453152027f),
                                       1.421413741f), -0.284496736f), 0.254829592f);
    float e = __builtin_amdgcn_exp2f(-z * z * 1.4426950408889634f);
    float erf = 1.0f - p * e;
    erf = copysignf(erf, v);
    return 0.5f * v * (1.0f + erf);
}

// ---------------------------------------------------------------------------
// K0: merged prep + norm1.
// Blocks 0..127: LDS-tiled transpose W1,W2 -> bf16 [out][in].
// Blocks 128..135: per-head RBS orthogonal -> worth_t (SCL folded), Wv^T.
// Blocks 136..143: colsum1 (8 blocks x 64 cols, row-parallel + LDS reduce).
// Blocks 144..4239: LayerNorm(512) of x -> xn bf16 + raw bf16 copy -> xb.
// ---------------------------------------------------------------------------
__global__ __launch_bounds__(256) void k_prep(const float* __restrict__ phi,
                                              const float* __restrict__ Wv,
                                              const float* __restrict__ W1,
                                              const float* __restrict__ W2,
                                              const float* __restrict__ x,
                                              __hip_bfloat16* __restrict__ worth_t,
                                              __hip_bfloat16* __restrict__ wvt,
                                              __hip_bfloat16* __restrict__ w1t,
                                              __hip_bfloat16* __restrict__ w2t,
                                              float* __restrict__ csum1,
                                              __hip_bfloat16* __restrict__ xn,
                                              __hip_bfloat16* __restrict__ xb) {
    __shared__ float sh[64 * 65];
    int tid = threadIdx.x;
    if (blockIdx.x >= 144) {
        // ---- norm1 path: wave per row ----
        int w = tid >> 6, l = tid & 63;
        size_t row = (size_t)(blockIdx.x - 144) * 4 + w;
        const float* p = x + row * 512 + l * 8;
        float4 v0 = *reinterpret_cast<const float4*>(p);
        float4 v1 = *reinterpret_cast<const float4*>(p + 4);
        float vv[8] = {v0.x, v0.y, v0.z, v0.w, v1.x, v1.y, v1.z, v1.w};
        bf8pack xo;
#pragma unroll
        for (int j = 0; j < 8; ++j) xo.v[j] = f2bf(vv[j]);
        *reinterpret_cast<bf8pack*>(xb + row * 512 + l * 8) = xo;
        float s = 0.f, sq = 0.f;
#pragma unroll
        for (int j = 0; j < 8; ++j) { s += vv[j]; sq += vv[j] * vv[j]; }
#pragma unroll
        for (int o = 32; o >= 1; o >>= 1) { s += __shfl_xor(s, o); sq += __shfl_xor(sq, o); }
        float mean = s * (1.0f / 512.0f);
        float var  = sq * (1.0f / 512.0f) - mean * mean;
        float rstd = rsqrtf(var + 1e-5f);
        bf8pack ob;
#pragma unroll
        for (int j = 0; j < 8; ++j) ob.v[j] = f2bf((vv[j] - mean) * rstd);
        *reinterpret_cast<bf8pack*>(xn + row * 512 + l * 8) = ob;
    } else if (blockIdx.x < 128) {
        int bid = blockIdx.x;
        const float* src = (bid & 1) ? W2 : W1;
        __hip_bfloat16* dst = (bid & 1) ? w2t : w1t;
        int tile = bid >> 1;
        int i0 = (tile & 7) * 64, o0 = (tile >> 3) * 64;
        float (*ts)[65] = (float(*)[65])sh;
        int r = tid >> 4, c4 = (tid & 15) * 4;
#pragma unroll
        for (int j4 = 0; j4 < 4; ++j4) {
            float4 v = *reinterpret_cast<const float4*>(&src[(size_t)(i0 + r + 16 * j4) * 512 + o0 + c4]);
            ts[r + 16 * j4][c4 + 0] = v.x; ts[r + 16 * j4][c4 + 1] = v.y;
            ts[r + 16 * j4][c4 + 2] = v.z; ts[r + 16 * j4][c4 + 3] = v.w;
        }
        __syncthreads();
        int o = tid >> 3, cg = tid & 7;
#pragma unroll
        for (int half = 0; half < 2; ++half) {
            int oo = o + 32 * half;
            bf8pack p;
#pragma unroll
            for (int j = 0; j < 8; ++j) p.v[j] = f2bf(ts[cg * 8 + j][oo]);
            *reinterpret_cast<bf8pack*>(&dst[(size_t)(o0 + oo) * 512 + i0 + cg * 8]) = p;
        }
    } else if (blockIdx.x < 136) {
        const float SCL = 0.18033688011112042f;  // log2(e)/8, folds softmax scale
        int h = blockIdx.x - 128;
        int t = tid;  // column index e
        if (t < 64) {
            for (int i = 0; i < 64; ++i) sh[i * 65 + t] = (i == t) ? 1.0f : 0.0f;
            for (int g = 0; g < 125; ++g) {
                int k = (g < 63) ? g : (124 - g);
                float ph = phi[h * 125 + g];
                float c, s;
                __sincosf(ph, &s, &c);
                float a  = sh[k * 65 + t];
                float b  = sh[(k + 1) * 65 + t];
                sh[k * 65 + t]       =  c * a + s * b;
                sh[(k + 1) * 65 + t] = -s * a + c * b;
            }
            for (int d = 0; d < 64; ++d)
                worth_t[h * 4096 + t * 64 + d] = f2bf(sh[d * 65 + t] * SCL);
            for (int d = 0; d < 64; ++d)
                wvt[h * 4096 + t * 64 + d] = f2bf(Wv[h * 4096 + d * 64 + t]);
        }
    } else {
        // colsum1: block covers 64 cols; 16 row-groups x 32 rows in parallel.
        int c0 = (blockIdx.x - 136) * 64;
        float (*acc)[68] = (float(*)[68])sh;   // [16][64+pad]
        int cg = (tid & 15) * 4, rg = tid >> 4;
        float4 s4 = {0.f, 0.f, 0.f, 0.f};
        for (int rr = 0; rr < 32; ++rr) {
            float4 v = *reinterpret_cast<const float4*>(&W1[(size_t)(rg * 32 + rr) * 512 + c0 + cg]);
            s4.x += v.x; s4.y += v.y; s4.z += v.z; s4.w += v.w;
        }
        acc[rg][cg + 0] = s4.x; acc[rg][cg + 1] = s4.y;
        acc[rg][cg + 2] = s4.z; acc[rg][cg + 3] = s4.w;
        __syncthreads();
        if (tid < 64) {
            float s = 0.f;
#pragma unroll
            for (int g = 0; g < 16; ++g) s += acc[g][tid];
            csum1[c0 + tid] = s;
        }
    }
}

// ---------------------------------------------------------------------------
// K2: per-head V projection via MFMA (V only; Q now computed inside k_attn).
// Output staged through padded LDS so all global stores are coalesced 16B.
// ---------------------------------------------------------------------------
__global__ __launch_bounds__(256) void k_proj(const __hip_bfloat16* __restrict__ xn,
                                              const __hip_bfloat16* __restrict__ wvt,
                                              const float* __restrict__ bv,
                                              __hip_bfloat16* __restrict__ vt) {
    int h = blockIdx.y, rt = blockIdx.x;
    int tid = threadIdx.x, w = tid >> 6, l = tid & 63;
    int lr = l & 15, lg = l >> 4;
    int nw = rt * 64 + w * 16;
    int b  = (rt * 64) >> 10;
    int n0 = (rt * 64) & 1023;
    size_t bh = (size_t)b * H_ + h;

    __shared__ __hip_bfloat16 vt_l[64 * 72];  // [e][n], stride 72

    const __hip_bfloat16* xp = xn + (size_t)(nw + lr) * 512 + h * 64 + lg * 8;
    bf16x8 xf0 = *reinterpret_cast<const bf16x8*>(xp);
    bf16x8 xf1 = *reinterpret_cast<const bf16x8*>(xp + 32);

    f32x4 accv[4] = {};
#pragma unroll
    for (int g = 0; g < 4; ++g) {
        const __hip_bfloat16* vp = wvt + h * 4096 + (g * 16 + lr) * 64 + lg * 8;
        accv[g] = MFMA16(xf0, *reinterpret_cast<const bf16x8*>(vp), accv[g]);
        accv[g] = MFMA16(xf1, *reinterpret_cast<const bf16x8*>(vp + 32), accv[g]);
    }
#pragma unroll
    for (int g = 0; g < 4; ++g) {
        float bb = bv[h * 64 + g * 16 + lr];
        bf4pack pv;
#pragma unroll
        for (int r = 0; r < 4; ++r) pv.v[r] = f2bf(accv[g][r] + bb);
        *reinterpret_cast<bf4pack*>(&vt_l[(g * 16 + lr) * 72 + w * 16 + lg * 4]) = pv;
    }
    __syncthreads();
    {
        int rr = tid >> 2, c0 = (tid & 3) * 16;
        bf8pack q0 = *reinterpret_cast<const bf8pack*>(&vt_l[rr * 72 + c0]);
        bf8pack q1 = *reinterpret_cast<const bf8pack*>(&vt_l[rr * 72 + c0 + 8]);
        __hip_bfloat16* d2 = vt + (bh * 64 + rr) * N_ + n0 + c0;
        *reinterpret_cast<bf8pack*>(d2)     = q0;
        *reinterpret_cast<bf8pack*>(d2 + 8) = q1;
    }
}

// ---------------------------------------------------------------------------
// K3: attention (r8/r13 loop, best measured). 8 waves, QBLK=256, KVBLK=128,
// double-buffered LDS. NEW: Q projection in-register in the prologue
// (overlaps STAGE(0) latency): Sq = mfma32(worth_t e-rows, xn q-rows) gives
// C[col=q][reg=e]; the proven PACK8 transform converts to the B-frag layout.
// Swapped QK^T 32x32x16, lane-local softmax (no max), setprio on MFMA.
// Epilogue: per-head LN(attn+xh)+xb -> res bf16.
// ---------------------------------------------------------------------------
__global__ __launch_bounds__(512, 4) void k_attn(const __hip_bfloat16* __restrict__ xn,
                                                 const __hip_bfloat16* __restrict__ worth_t,
                                                 const __hip_bfloat16* __restrict__ vt,
                                                 const __hip_bfloat16* __restrict__ xb,
                                                 __hip_bfloat16* __restrict__ res) {
    int h = blockIdx.x, b = blockIdx.z;
    int tid = threadIdx.x;
    int w = tid >> 6, l = tid & 63;
    int lq = l & 31, hi = l >> 5;
    int q0 = blockIdx.y * 256 + w * 32;
    size_t bh = (size_t)b * H_ + h;

    __shared__ __hip_bfloat16 kb[2][128 * 64];  // [kv 128][d 64]
    __shared__ __hip_bfloat16 vb[2][64 * 128];  // [d 64][kv 128]
    __shared__ float lred[8][32];

    int krow = w * 16 + (l >> 3);
    const __hip_bfloat16* ksrc = xn + ((size_t)b * N_ + krow) * 512 + h * 64
                               + (((l & 7) ^ (krow & 7)) << 3);
    int vrow0 = w * 8 + (l >> 4);
    int vrow1 = vrow0 + 4;
    const __hip_bfloat16* vsrc0 = vt + (bh * 64 + vrow0) * N_ + (((l & 15) ^ (vrow0 & 15)) << 3);
    const __hip_bfloat16* vsrc1 = vt + (bh * 64 + vrow1) * N_ + (((l & 15) ^ (vrow1 & 15)) << 3);

#define STAGE(t) do { int bf_ = (t) & 1; \
        gload16(ksrc + (size_t)((t) * 128) * 512,     &kb[bf_][(w * 16) * 64]); \
        gload16(ksrc + (size_t)((t) * 128 + 8) * 512, &kb[bf_][(w * 16 + 8) * 64]); \
        gload16(vsrc0 + (t) * 128, &vb[bf_][(w * 8) * 128]); \
        gload16(vsrc1 + (t) * 128, &vb[bf_][(w * 8 + 4) * 128]); } while (0)
#define TILE_BAR() do { \
        asm volatile("s_waitcnt vmcnt(0)" ::: "memory"); \
        __builtin_amdgcn_s_barrier(); \
        __builtin_amdgcn_sched_barrier(0); } while (0)

    // ---- issue first stage, then compute Q in-register under its latency ----
    STAGE(0);

    bf16x8 qf0, qf1, qf2, qf3;
    {
        // A-frag: worth_t rows e (m = lane&31 -> e_local), k = d (8*hi+j +16kd)
        // B-frag: xn rows q (col = lane&31 -> q), k = d
        const __hip_bfloat16* xqp = xn + ((size_t)b * N_ + q0 + lq) * 512 + h * 64 + 8 * hi;
        const __hip_bfloat16* wt0 = worth_t + h * 4096 + lq * 64 + 8 * hi;   // e = lq
        const __hip_bfloat16* wt1 = wt0 + 32 * 64;                           // e = lq + 32
        f32x16 sq0 = {}, sq1 = {};
#pragma unroll
        for (int kd = 0; kd < 4; ++kd) {
            bf16x8 xq = *reinterpret_cast<const bf16x8*>(xqp + kd * 16);
            sq0 = MFMA32(*reinterpret_cast<const bf16x8*>(wt0 + kd * 16), xq, sq0);
            sq1 = MFMA32(*reinterpret_cast<const bf16x8*>(wt1 + kd * 16), xq, sq1);
        }
        // qf[kd] elem j at e = kd*16 + 8*hi + j -- identical transform to pa
        PACK8(qf0, sq0, 0);
        PACK8(qf1, sq0, 8);
        PACK8(qf2, sq1, 0);
        PACK8(qf3, sq1, 8);
    }

    f32x16 o0 = {}, o1 = {};
    float l_run = 0.f;
    int kso = lq & 7;
    int vso = lq & 15;

    auto body = [&](int bf_, int mm) {
        const __hip_bfloat16* kc = &kb[bf_][mm * 64 * 64];
        const __hip_bfloat16* vc = &vb[bf_][0];
        f32x16 s0 = {}, s1 = {};
        __builtin_amdgcn_s_setprio(1);
#pragma unroll
        for (int kd = 0; kd < 4; ++kd) {
            bf16x8 qf = (kd == 0) ? qf0 : (kd == 1) ? qf1 : (kd == 2) ? qf2 : qf3;
            int sl = ((kd * 2 + hi) ^ kso) << 3;
            bf16x8 ka0 = *reinterpret_cast<const bf16x8*>(kc + lq * 64 + sl);
            bf16x8 ka1 = *reinterpret_cast<const bf16x8*>(kc + (lq + 32) * 64 + sl);
            s0 = MFMA32(ka0, qf, s0);
            s1 = MFMA32(ka1, qf, s1);
        }
        __builtin_amdgcn_s_setprio(0);
#pragma unroll
        for (int i = 0; i < 16; ++i) {
            s0[i] = __builtin_amdgcn_exp2f(s0[i]);
            s1[i] = __builtin_amdgcn_exp2f(s1[i]);
        }
        float ls = 0.f;
#pragma unroll
        for (int i = 0; i < 16; ++i) ls += s0[i] + s1[i];
        l_run += ls;
        bf16x8 pa[4];
        PACK8(pa[0], s0, 0);
        PACK8(pa[1], s0, 8);
        PACK8(pa[2], s1, 0);
        PACK8(pa[3], s1, 8);
        __builtin_amdgcn_s_setprio(1);
#pragma unroll
        for (int ks = 0; ks < 4; ++ks) {
            int sl = ((mm * 8 + ks * 2 + hi) ^ vso) << 3;
            bf16x8 v0 = *reinterpret_cast<const bf16x8*>(vc + lq * 128 + sl);
            bf16x8 v1 = *reinterpret_cast<const bf16x8*>(vc + (lq + 32) * 128 + sl);
            o0 = MFMA32(pa[ks], v0, o0);
            o1 = MFMA32(pa[ks], v1, o1);
        }
        __builtin_amdgcn_s_setprio(0);
    };

    TILE_BAR();
    for (int t = 0; t < 7; ++t) {
        STAGE(t + 1);
        body(t & 1, 0);
        body(t & 1, 1);
        TILE_BAR();
    }
    body(1, 0);
    body(1, 1);

    // ---- finalize: per-head LN(attn + xh) + xb -> res (bf16) ----
    float lt = l_run + __shfl_xor(l_run, 32);
    if (hi == 0) lred[w][lq] = 1.0f / lt;
#pragma unroll
    for (int r = 0; r < 16; ++r) {
        int qr = (r & 3) + 8 * (r >> 2) + 4 * hi;
        float li = lred[w][qr];
        size_t base = ((size_t)b * N_ + q0 + qr) * 512 + h * 64;
        float t0 = o0[r] * li + bf2f(xn[base + lq]);
        float t1 = o1[r] * li + bf2f(xn[base + 32 + lq]);
        float s1v = t0 + t1, s2v = t0 * t0 + t1 * t1;
#pragma unroll
        for (int off = 16; off >= 1; off >>= 1) { s1v += __shfl_xor(s1v, off); s2v += __shfl_xor(s2v, off); }
        float mean = s1v * (1.0f / 64.0f);
        float var  = s2v * (1.0f / 64.0f) - mean * mean;
        float rstd = rsqrtf(var + 1e-5f);
        res[base + lq]      = f2bf((t0 - mean) * rstd + bf2f(xb[base + lq]));
        res[base + 32 + lq] = f2bf((t1 - mean) * rstd + bf2f(xb[base + 32 + lq]));
    }
#undef STAGE
#undef TILE_BAR
}

// ---------------------------------------------------------------------------
// K5/K6: GEMM 16384x512x512, bf16 MFMA (r10 structure, proven). Block =
// 128x64 tile, 4 waves x 32 rows. Bt panel staged in k-chunks of 128
// (2 x 16 KB LDS, double-buffered). Grid (rt=128, ct=8): XCD = rt%8.
// MODE 0: LN stats in transient prologue (2-VGPR carry, __shfl routing);
//         out = gelu(acc*rstd + b1 - mean*rstd*csum) -> bf16.
// MODE 1: out = A@Bt^T + bias + res -> f32.
// ---------------------------------------------------------------------------
template <int MODE>
__global__ __launch_bounds__(256, 5) void k_gemm(const __hip_bfloat16* __restrict__ A,
                                                 const __hip_bfloat16* __restrict__ Bt,
                                                 const float* __restrict__ bias,
                                                 const __hip_bfloat16* __restrict__ resid,
                                                 const float* __restrict__ csum,
                                                 __hip_bfloat16* __restrict__ outb,
                                                 float* __restrict__ outf) {
    int m0 = blockIdx.x * 128, nn0 = blockIdx.y * 64;
    int tid = threadIdx.x, w = tid >> 6, l = tid & 63;
    int lr = l & 15, lg = l >> 4;
    __shared__ __hip_bfloat16 bs[2][64 * 128];  // 32 KB total

    int srow = w * 16 + (l >> 4);
    int sslot = l & 15;

#define GSTAGE(c) do { \
        _Pragma("unroll") \
        for (int i_ = 0; i_ < 4; ++i_) { \
            int row_ = srow + i_ * 4; \
            gload16(Bt + (size_t)(nn0 + row_) * 512 + (c) * 128 + ((sslot ^ (row_ & 15)) << 3), \
                    &bs[(c) & 1][(w * 16 + i_ * 4) * 128]); \
        } } while (0)

    GSTAGE(0);

    // ---- transient LN-stat prologue (MODE 0): wave w covers rows w*32..+31 ----
    float rstd_reg = 0.f, mr_reg = 0.f;
    if constexpr (MODE == 0) {
#pragma unroll 4
        for (int i = 0; i < 32; ++i) {
            bf16x8 u = *reinterpret_cast<const bf16x8*>(
                A + (size_t)(m0 + w * 32 + i) * 512 + l * 8);
            float s = 0.f, sq = 0.f;
#pragma unroll
            for (int j = 0; j < 8; ++j) { float a = (float)u[j]; s += a; sq = fmaf(a, a, sq); }
#pragma unroll
            for (int o = 32; o >= 1; o >>= 1) { s += __shfl_xor(s, o); sq += __shfl_xor(sq, o); }
            float mean = s * (1.0f / 512.0f);
            float var  = sq * (1.0f / 512.0f) - mean * mean;
            float rstd = rsqrtf(var + 1e-5f);
            if ((l & 31) == i) { rstd_reg = rstd; mr_reg = mean * rstd; }
        }
    }

    asm volatile("s_waitcnt vmcnt(0)" ::: "memory");
    __builtin_amdgcn_s_barrier();
    __builtin_amdgcn_sched_barrier(0);

    f32x4 acc0[4] = {}, acc1[4] = {};
    const __hip_bfloat16* ap0 = A + (size_t)(m0 + w * 32 + lr) * 512 + lg * 8;
    const __hip_bfloat16* ap1 = ap0 + 16 * 512;
#pragma unroll
    for (int c = 0; c < 4; ++c) {
        if (c < 3) GSTAGE(c + 1);
        const __hip_bfloat16* bc = &bs[c & 1][0];
#pragma unroll
        for (int kk = 0; kk < 4; ++kk) {
            bf16x8 a0 = *reinterpret_cast<const bf16x8*>(ap0 + c * 128 + kk * 32);
            bf16x8 a1 = *reinterpret_cast<const bf16x8*>(ap1 + c * 128 + kk * 32);
#pragma unroll
            for (int g = 0; g < 4; ++g) {
                int row = g * 16 + lr;
                bf16x8 bf = *reinterpret_cast<const bf16x8*>(
                    bc + row * 128 + (((kk * 4 + lg) ^ (row & 15)) << 3));
                acc0[g] = MFMA16(a0, bf, acc0[g]);
                acc1[g] = MFMA16(a1, bf, acc1[g]);
            }
        }
        if (c < 3) {
            asm volatile("s_waitcnt vmcnt(0)" ::: "memory");
            __builtin_amdgcn_s_barrier();
            __builtin_amdgcn_sched_barrier(0);
        }
    }
#undef GSTAGE
#pragma unroll
    for (int g = 0; g < 4; ++g) {
        int col = nn0 + g * 16 + lr;
        float bb = bias[col];
        float cc = (MODE == 0) ? csum[col] : 0.f;
#pragma unroll
        for (int r = 0; r < 4; ++r) {
            int row0 = m0 + w * 32 + lg * 4 + r;
            if (MODE == 0) {
                float rs0 = __shfl(rstd_reg, lg * 4 + r);
                float mr0 = __shfl(mr_reg,  lg * 4 + r);
                float rs1 = __shfl(rstd_reg, lg * 4 + r + 16);
                float mr1 = __shfl(mr_reg,  lg * 4 + r + 16);
                float v0 = fmaf(acc0[g][r], rs0, fmaf(-mr0, cc, bb));
                float v1 = fmaf(acc1[g][r], rs1, fmaf(-mr1, cc, bb));
                outb[(size_t)row0 * 512 + col] = f2bf(gelu_f(v0));
                outb[(size_t)(row0 + 16) * 512 + col] = f2bf(gelu_f(v1));
            } else {
                size_t i0 = (size_t)row0 * 512 + col;
                size_t i1 = (size_t)(row0 + 16) * 512 + col;
                outf[i0] = acc0[g][r] + bb + bf2f(resid[i0]);
                outf[i1] = acc1[g][r] + bb + bf2f(resid[i1]);
            }
        }
    }
}

// ---------------------------------------------------------------------------
extern "C" void kernel_launch(void* const* d_in, const int* in_sizes, int n_in,
                              void* d_out, int out_size, void* d_ws, size_t ws_size,
                              hipStream_t stream) {
    const float* x   = (const float*)d_in[0];
    const float* Wv  = (const float*)d_in[1];
    const float* bv  = (const float*)d_in[2];
    const float* phi = (const float*)d_in[3];
    const float* W1  = (const float*)d_in[4];
    const float* b1  = (const float*)d_in[5];
    const float* W2  = (const float*)d_in[6];
    const float* b2  = (const float*)d_in[7];
    float* out = (float*)d_out;

    char* ws = (char*)d_ws;
    __hip_bfloat16* worth_t = (__hip_bfloat16*)(ws + 0);          // 64 KB
    __hip_bfloat16* wvt     = (__hip_bfloat16*)(ws + 65536);      // 64 KB
    __hip_bfloat16* w1t     = (__hip_bfloat16*)(ws + 131072);     // 512 KB
    __hip_bfloat16* w2t     = (__hip_bfloat16*)(ws + 655360);     // 512 KB
    float*          csum1   = (float*)(ws + 1179648);             // 2 KB
    __hip_bfloat16* xn      = (__hip_bfloat16*)(ws + 1312768);    // 16 MB
    __hip_bfloat16* vt      = (__hip_bfloat16*)(ws + 18089984);   // 16 MB
    __hip_bfloat16* res     = (__hip_bfloat16*)(ws + 34867200);   // 16 MB
    __hip_bfloat16* y1      = (__hip_bfloat16*)(ws + 51644416);   // 16 MB
    __hip_bfloat16* xb      = (__hip_bfloat16*)(ws + 68421632);   // 16 MB

    k_prep<<<dim3(4240), dim3(256), 0, stream>>>(phi, Wv, W1, W2, x,
                                                 worth_t, wvt, w1t, w2t, csum1, xn, xb);
    k_proj<<<dim3(256, 8), dim3(256), 0, stream>>>(xn, wvt, bv, vt);
    k_attn<<<dim3(8, 4, 16), dim3(512), 0, stream>>>(xn, worth_t, vt, xb, res);
    k_gemm<0><<<dim3(128, 8), dim3(256), 0, stream>>>(res, w1t, b1, nullptr, csum1, y1, nullptr);
    k_gemm<1><<<dim3(128, 8), dim3(256), 0, stream>>>(y1, w2t, b2, res, nullptr, nullptr, out);
}

// Round 18
// 146.807 us; speedup vs baseline: 1.0627x; 1.0012x over previous
//
#include <hip/hip_runtime.h>
#include <hip/hip_bf16.h>
#include <math.h>

// Problem constants
#define B_  16
#define N_  1024
#define E_  512
#define H_  8

typedef __attribute__((ext_vector_type(8)))  __bf16 bf16x8;
typedef __attribute__((ext_vector_type(4)))  float  f32x4;
typedef __attribute__((ext_vector_type(16))) float  f32x16;
typedef __attribute__((ext_vector_type(4)))  unsigned int u32x4;

struct alignas(16) bf8pack { __hip_bfloat16 v[8]; };
struct alignas(8)  bf4pack { __hip_bfloat16 v[4]; };

static __device__ __forceinline__ float bf2f(__hip_bfloat16 x) { return __bfloat162float(x); }
static __device__ __forceinline__ __hip_bfloat16 f2bf(float x) { return __float2bfloat16(x); }

static __device__ __forceinline__ unsigned pkbf(float lo, float hi) {
    unsigned r;
    asm("v_cvt_pk_bf16_f32 %0, %1, %2" : "=v"(r) : "v"(lo), "v"(hi));
    return r;
}
// v_permlane32_swap_b32 a, b:  a' = [a.lo32, b.lo32], b' = [a.hi32, b.hi32]
static __device__ __forceinline__ void swap32(unsigned &a, unsigned &b) {
    asm("v_permlane32_swap_b32 %0, %1" : "+v"(a), "+v"(b));
}
// async global->LDS, 16B per lane. LDS dest is wave-uniform base + lane*16.
static __device__ __forceinline__ void gload16(const __hip_bfloat16* g, __hip_bfloat16* l) {
    __builtin_amdgcn_global_load_lds(
        (const __attribute__((address_space(1))) unsigned*)g,
        (__attribute__((address_space(3))) unsigned*)l, 16, 0, 0);
}
#define MFMA32(a, b, c) __builtin_amdgcn_mfma_f32_32x32x16_bf16((a), (b), (c), 0, 0, 0)
#define MFMA16(a, b, c) __builtin_amdgcn_mfma_f32_16x16x32_bf16((a), (b), (c), 0, 0, 0)

// C(32x32)->frag repack (proven in P->pa path): input 8 f32 (C regs r: idx
// (r&3)+8*(r>>2)+4*hi), output bf16x8 frag elem j at idx 8*hi+j (A/B layout).
#define PACK8(dst, s, base) do { \
        unsigned u0 = pkbf((s)[(base)+0], (s)[(base)+1]), u1 = pkbf((s)[(base)+2], (s)[(base)+3]); \
        unsigned u2 = pkbf((s)[(base)+4], (s)[(base)+5]), u3 = pkbf((s)[(base)+6], (s)[(base)+7]); \
        swap32(u0, u2); swap32(u1, u3); \
        u32x4 uu = {u0, u1, u2, u3}; \
        dst = __builtin_bit_cast(bf16x8, uu); } while (0)

// exact-grade GELU: erf via Abramowitz-Stegun 7.1.26 (|err| < 1.5e-7)
static __device__ __forceinline__ float gelu_f(float v) {
    float z = fabsf(v) * 0.70710678118654752f;
    float t = 1.0f / fmaf(0.3275911f, z, 1.0f);
    float p = t * fmaf(t, fmaf(t, fmaf(t, fmaf(t, 1.061405429f, -1.453152027f),
                                       1.421413741f), -0.284496736f), 0.254829592f);
    float e = __builtin_amdgcn_exp2f(-z * z * 1.4426950408889634f);
    float erf = 1.0f - p * e;
    erf = copysignf(erf, v);
    return 0.5f * v * (1.0f + erf);
}

// ---------------------------------------------------------------------------
// K0: merged prep + norm1.
// Blocks 0..127: LDS-tiled transpose W1,W2 -> bf16 [out][in].
// Blocks 128..135: per-head RBS orthogonal -> worth_t (SCL folded), Wv^T.
// Blocks 136..143: colsum1 (8 blocks x 64 cols, row-parallel + LDS reduce).
// Blocks 144..4239: LayerNorm(512) of x -> xn bf16 + raw bf16 copy -> xb.
// ---------------------------------------------------------------------------
__global__ __launch_bounds__(256) void k_prep(const float* __restrict__ phi,
                                              const float* __restrict__ Wv,
                                              const float* __restrict__ W1,
                                              const float* __restrict__ W2,
                                              const float* __restrict__ x,
                                              __hip_bfloat16* __restrict__ worth_t,
                                              __hip_bfloat16* __restrict__ wvt,
                                              __hip_bfloat16* __restrict__ w1t,
                                              __hip_bfloat16* __restrict__ w2t,
                                              float* __restrict__ csum1,
                                              __hip_bfloat16* __restrict__ xn,
                                              __hip_bfloat16* __restrict__ xb) {
    __shared__ float sh[64 * 65];
    int tid = threadIdx.x;
    if (blockIdx.x >= 144) {
        // ---- norm1 path: wave per row ----
        int w = tid >> 6, l = tid & 63;
        size_t row = (size_t)(blockIdx.x - 144) * 4 + w;
        const float* p = x + row * 512 + l * 8;
        float4 v0 = *reinterpret_cast<const float4*>(p);
        float4 v1 = *reinterpret_cast<const float4*>(p + 4);
        float vv[8] = {v0.x, v0.y, v0.z, v0.w, v1.x, v1.y, v1.z, v1.w};
        bf8pack xo;
#pragma unroll
        for (int j = 0; j < 8; ++j) xo.v[j] = f2bf(vv[j]);
        *reinterpret_cast<bf8pack*>(xb + row * 512 + l * 8) = xo;
        float s = 0.f, sq = 0.f;
#pragma unroll
        for (int j = 0; j < 8; ++j) { s += vv[j]; sq += vv[j] * vv[j]; }
#pragma unroll
        for (int o = 32; o >= 1; o >>= 1) { s += __shfl_xor(s, o); sq += __shfl_xor(sq, o); }
        float mean = s * (1.0f / 512.0f);
        float var  = sq * (1.0f / 512.0f) - mean * mean;
        float rstd = rsqrtf(var + 1e-5f);
        bf8pack ob;
#pragma unroll
        for (int j = 0; j < 8; ++j) ob.v[j] = f2bf((vv[j] - mean) * rstd);
        *reinterpret_cast<bf8pack*>(xn + row * 512 + l * 8) = ob;
    } else if (blockIdx.x < 128) {
        int bid = blockIdx.x;
        const float* src = (bid & 1) ? W2 : W1;
        __hip_bfloat16* dst = (bid & 1) ? w2t : w1t;
        int tile = bid >> 1;
        int i0 = (tile & 7) * 64, o0 = (tile >> 3) * 64;
        float (*ts)[65] = (float(*)[65])sh;
        int r = tid >> 4, c4 = (tid & 15) * 4;
#pragma unroll
        for (int j4 = 0; j4 < 4; ++j4) {
            float4 v = *reinterpret_cast<const float4*>(&src[(size_t)(i0 + r + 16 * j4) * 512 + o0 + c4]);
            ts[r + 16 * j4][c4 + 0] = v.x; ts[r + 16 * j4][c4 + 1] = v.y;
            ts[r + 16 * j4][c4 + 2] = v.z; ts[r + 16 * j4][c4 + 3] = v.w;
        }
        __syncthreads();
        int o = tid >> 3, cg = tid & 7;
#pragma unroll
        for (int half = 0; half < 2; ++half) {
            int oo = o + 32 * half;
            bf8pack p;
#pragma unroll
            for (int j = 0; j < 8; ++j) p.v[j] = f2bf(ts[cg * 8 + j][oo]);
            *reinterpret_cast<bf8pack*>(&dst[(size_t)(o0 + oo) * 512 + i0 + cg * 8]) = p;
        }
    } else if (blockIdx.x < 136) {
        const float SCL = 0.18033688011112042f;  // log2(e)/8, folds softmax scale
        int h = blockIdx.x - 128;
        int t = tid;  // column index e
        if (t < 64) {
            for (int i = 0; i < 64; ++i) sh[i * 65 + t] = (i == t) ? 1.0f : 0.0f;
            for (int g = 0; g < 125; ++g) {
                int k = (g < 63) ? g : (124 - g);
                float ph = phi[h * 125 + g];
                float c, s;
                __sincosf(ph, &s, &c);
                float a  = sh[k * 65 + t];
                float b  = sh[(k + 1) * 65 + t];
                sh[k * 65 + t]       =  c * a + s * b;
                sh[(k + 1) * 65 + t] = -s * a + c * b;
            }
            for (int d = 0; d < 64; ++d)
                worth_t[h * 4096 + t * 64 + d] = f2bf(sh[d * 65 + t] * SCL);
            for (int d = 0; d < 64; ++d)
                wvt[h * 4096 + t * 64 + d] = f2bf(Wv[h * 4096 + d * 64 + t]);
        }
    } else {
        // colsum1: block covers 64 cols; 16 row-groups x 32 rows in parallel.
        int c0 = (blockIdx.x - 136) * 64;
        float (*acc)[68] = (float(*)[68])sh;   // [16][64+pad]
        int cg = (tid & 15) * 4, rg = tid >> 4;
        float4 s4 = {0.f, 0.f, 0.f, 0.f};
        for (int rr = 0; rr < 32; ++rr) {
            float4 v = *reinterpret_cast<const float4*>(&W1[(size_t)(rg * 32 + rr) * 512 + c0 + cg]);
            s4.x += v.x; s4.y += v.y; s4.z += v.z; s4.w += v.w;
        }
        acc[rg][cg + 0] = s4.x; acc[rg][cg + 1] = s4.y;
        acc[rg][cg + 2] = s4.z; acc[rg][cg + 3] = s4.w;
        __syncthreads();
        if (tid < 64) {
            float s = 0.f;
#pragma unroll
            for (int g = 0; g < 16; ++g) s += acc[g][tid];
            csum1[c0 + tid] = s;
        }
    }
}

// ---------------------------------------------------------------------------
// K2: per-head V projection via MFMA (V only; Q computed inside k_attn).
// Output staged through padded LDS so all global stores are coalesced 16B.
// ---------------------------------------------------------------------------
__global__ __launch_bounds__(256) void k_proj(const __hip_bfloat16* __restrict__ xn,
                                              const __hip_bfloat16* __restrict__ wvt,
                                              const float* __restrict__ bv,
                                              __hip_bfloat16* __restrict__ vt) {
    int h = blockIdx.y, rt = blockIdx.x;
    int tid = threadIdx.x, w = tid >> 6, l = tid & 63;
    int lr = l & 15, lg = l >> 4;
    int nw = rt * 64 + w * 16;
    int b  = (rt * 64) >> 10;
    int n0 = (rt * 64) & 1023;
    size_t bh = (size_t)b * H_ + h;

    __shared__ __hip_bfloat16 vt_l[64 * 72];  // [e][n], stride 72

    const __hip_bfloat16* xp = xn + (size_t)(nw + lr) * 512 + h * 64 + lg * 8;
    bf16x8 xf0 = *reinterpret_cast<const bf16x8*>(xp);
    bf16x8 xf1 = *reinterpret_cast<const bf16x8*>(xp + 32);

    f32x4 accv[4] = {};
#pragma unroll
    for (int g = 0; g < 4; ++g) {
        const __hip_bfloat16* vp = wvt + h * 4096 + (g * 16 + lr) * 64 + lg * 8;
        accv[g] = MFMA16(xf0, *reinterpret_cast<const bf16x8*>(vp), accv[g]);
        accv[g] = MFMA16(xf1, *reinterpret_cast<const bf16x8*>(vp + 32), accv[g]);
    }
#pragma unroll
    for (int g = 0; g < 4; ++g) {
        float bb = bv[h * 64 + g * 16 + lr];
        bf4pack pv;
#pragma unroll
        for (int r = 0; r < 4; ++r) pv.v[r] = f2bf(accv[g][r] + bb);
        *reinterpret_cast<bf4pack*>(&vt_l[(g * 16 + lr) * 72 + w * 16 + lg * 4]) = pv;
    }
    __syncthreads();
    {
        int rr = tid >> 2, c0 = (tid & 3) * 16;
        bf8pack q0 = *reinterpret_cast<const bf8pack*>(&vt_l[rr * 72 + c0]);
        bf8pack q1 = *reinterpret_cast<const bf8pack*>(&vt_l[rr * 72 + c0 + 8]);
        __hip_bfloat16* d2 = vt + (bh * 64 + rr) * N_ + n0 + c0;
        *reinterpret_cast<bf8pack*>(d2)     = q0;
        *reinterpret_cast<bf8pack*>(d2 + 8) = q1;
    }
}

// ---------------------------------------------------------------------------
// K3: attention (r8/r13 loop, best measured). 8 waves, QBLK=256, KVBLK=128,
// double-buffered LDS. Q projection in-register in the prologue (overlaps
// STAGE(0) latency): Sq = mfma32(worth_t e-rows, xn q-rows) gives
// C[col=q][reg=e]; PACK8 converts to the B-frag layout.
// Swapped QK^T 32x32x16, lane-local softmax (no max), setprio on MFMA.
// Epilogue: per-head LN(attn+xh)+xb -> res bf16.
// ---------------------------------------------------------------------------
__global__ __launch_bounds__(512, 4) void k_attn(const __hip_bfloat16* __restrict__ xn,
                                                 const __hip_bfloat16* __restrict__ worth_t,
                                                 const __hip_bfloat16* __restrict__ vt,
                                                 const __hip_bfloat16* __restrict__ xb,
                                                 __hip_bfloat16* __restrict__ res) {
    int h = blockIdx.x, b = blockIdx.z;
    int tid = threadIdx.x;
    int w = tid >> 6, l = tid & 63;
    int lq = l & 31, hi = l >> 5;
    int q0 = blockIdx.y * 256 + w * 32;
    size_t bh = (size_t)b * H_ + h;

    __shared__ __hip_bfloat16 kb[2][128 * 64];  // [kv 128][d 64]
    __shared__ __hip_bfloat16 vb[2][64 * 128];  // [d 64][kv 128]
    __shared__ float lred[8][32];

    int krow = w * 16 + (l >> 3);
    const __hip_bfloat16* ksrc = xn + ((size_t)b * N_ + krow) * 512 + h * 64
                               + (((l & 7) ^ (krow & 7)) << 3);
    int vrow0 = w * 8 + (l >> 4);
    int vrow1 = vrow0 + 4;
    const __hip_bfloat16* vsrc0 = vt + (bh * 64 + vrow0) * N_ + (((l & 15) ^ (vrow0 & 15)) << 3);
    const __hip_bfloat16* vsrc1 = vt + (bh * 64 + vrow1) * N_ + (((l & 15) ^ (vrow1 & 15)) << 3);

#define STAGE(t) do { int bf_ = (t) & 1; \
        gload16(ksrc + (size_t)((t) * 128) * 512,     &kb[bf_][(w * 16) * 64]); \
        gload16(ksrc + (size_t)((t) * 128 + 8) * 512, &kb[bf_][(w * 16 + 8) * 64]); \
        gload16(vsrc0 + (t) * 128, &vb[bf_][(w * 8) * 128]); \
        gload16(vsrc1 + (t) * 128, &vb[bf_][(w * 8 + 4) * 128]); } while (0)
#define TILE_BAR() do { \
        asm volatile("s_waitcnt vmcnt(0)" ::: "memory"); \
        __builtin_amdgcn_s_barrier(); \
        __builtin_amdgcn_sched_barrier(0); } while (0)

    // ---- issue first stage, then compute Q in-register under its latency ----
    STAGE(0);

    bf16x8 qf0, qf1, qf2, qf3;
    {
        const __hip_bfloat16* xqp = xn + ((size_t)b * N_ + q0 + lq) * 512 + h * 64 + 8 * hi;
        const __hip_bfloat16* wt0 = worth_t + h * 4096 + lq * 64 + 8 * hi;   // e = lq
        const __hip_bfloat16* wt1 = wt0 + 32 * 64;                           // e = lq + 32
        f32x16 sq0 = {}, sq1 = {};
#pragma unroll
        for (int kd = 0; kd < 4; ++kd) {
            bf16x8 xq = *reinterpret_cast<const bf16x8*>(xqp + kd * 16);
            sq0 = MFMA32(*reinterpret_cast<const bf16x8*>(wt0 + kd * 16), xq, sq0);
            sq1 = MFMA32(*reinterpret_cast<const bf16x8*>(wt1 + kd * 16), xq, sq1);
        }
        PACK8(qf0, sq0, 0);
        PACK8(qf1, sq0, 8);
        PACK8(qf2, sq1, 0);
        PACK8(qf3, sq1, 8);
    }

    f32x16 o0 = {}, o1 = {};
    float l_run = 0.f;
    int kso = lq & 7;
    int vso = lq & 15;

    auto body = [&](int bf_, int mm) {
        const __hip_bfloat16* kc = &kb[bf_][mm * 64 * 64];
        const __hip_bfloat16* vc = &vb[bf_][0];
        f32x16 s0 = {}, s1 = {};
        __builtin_amdgcn_s_setprio(1);
#pragma unroll
        for (int kd = 0; kd < 4; ++kd) {
            bf16x8 qf = (kd == 0) ? qf0 : (kd == 1) ? qf1 : (kd == 2) ? qf2 : qf3;
            int sl = ((kd * 2 + hi) ^ kso) << 3;
            bf16x8 ka0 = *reinterpret_cast<const bf16x8*>(kc + lq * 64 + sl);
            bf16x8 ka1 = *reinterpret_cast<const bf16x8*>(kc + (lq + 32) * 64 + sl);
            s0 = MFMA32(ka0, qf, s0);
            s1 = MFMA32(ka1, qf, s1);
        }
        __builtin_amdgcn_s_setprio(0);
#pragma unroll
        for (int i = 0; i < 16; ++i) {
            s0[i] = __builtin_amdgcn_exp2f(s0[i]);
            s1[i] = __builtin_amdgcn_exp2f(s1[i]);
        }
        float ls = 0.f;
#pragma unroll
        for (int i = 0; i < 16; ++i) ls += s0[i] + s1[i];
        l_run += ls;
        bf16x8 pa[4];
        PACK8(pa[0], s0, 0);
        PACK8(pa[1], s0, 8);
        PACK8(pa[2], s1, 0);
        PACK8(pa[3], s1, 8);
        __builtin_amdgcn_s_setprio(1);
#pragma unroll
        for (int ks = 0; ks < 4; ++ks) {
            int sl = ((mm * 8 + ks * 2 + hi) ^ vso) << 3;
            bf16x8 v0 = *reinterpret_cast<const bf16x8*>(vc + lq * 128 + sl);
            bf16x8 v1 = *reinterpret_cast<const bf16x8*>(vc + (lq + 32) * 128 + sl);
            o0 = MFMA32(pa[ks], v0, o0);
            o1 = MFMA32(pa[ks], v1, o1);
        }
        __builtin_amdgcn_s_setprio(0);
    };

    TILE_BAR();
    for (int t = 0; t < 7; ++t) {
        STAGE(t + 1);
        body(t & 1, 0);
        body(t & 1, 1);
        TILE_BAR();
    }
    body(1, 0);
    body(1, 1);

    // ---- finalize: per-head LN(attn + xh) + xb -> res (bf16) ----
    float lt = l_run + __shfl_xor(l_run, 32);
    if (hi == 0) lred[w][lq] = 1.0f / lt;
#pragma unroll
    for (int r = 0; r < 16; ++r) {
        int qr = (r & 3) + 8 * (r >> 2) + 4 * hi;
        float li = lred[w][qr];
        size_t base = ((size_t)b * N_ + q0 + qr) * 512 + h * 64;
        float t0 = o0[r] * li + bf2f(xn[base + lq]);
        float t1 = o1[r] * li + bf2f(xn[base + 32 + lq]);
        float s1v = t0 + t1, s2v = t0 * t0 + t1 * t1;
#pragma unroll
        for (int off = 16; off >= 1; off >>= 1) { s1v += __shfl_xor(s1v, off); s2v += __shfl_xor(s2v, off); }
        float mean = s1v * (1.0f / 64.0f);
        float var  = s2v * (1.0f / 64.0f) - mean * mean;
        float rstd = rsqrtf(var + 1e-5f);
        res[base + lq]      = f2bf((t0 - mean) * rstd + bf2f(xb[base + lq]));
        res[base + 32 + lq] = f2bf((t1 - mean) * rstd + bf2f(xb[base + 32 + lq]));
    }
#undef STAGE
#undef TILE_BAR
}

// ---------------------------------------------------------------------------
// K5/K6: GEMM 16384x512x512, bf16 MFMA (r10 structure, proven). Block =
// 128x64 tile, 4 waves x 32 rows. Bt panel staged in k-chunks of 128
// (2 x 16 KB LDS, double-buffered). Grid (rt=128, ct=8): XCD = rt%8.
// MODE 0: LN stats in transient prologue (2-VGPR carry, __shfl routing);
//         out = gelu(acc*rstd + b1 - mean*rstd*csum) -> bf16.
// MODE 1: out = A@Bt^T + bias + res -> f32.
// ---------------------------------------------------------------------------
template <int MODE>
__global__ __launch_bounds__(256, 5) void k_gemm(const __hip_bfloat16* __restrict__ A,
                                                 const __hip_bfloat16* __restrict__ Bt,
                                                 const float* __restrict__ bias,
                                                 const __hip_bfloat16* __restrict__ resid,
                                                 const float* __restrict__ csum,
                                                 __hip_bfloat16* __restrict__ outb,
                                                 float* __restrict__ outf) {
    int m0 = blockIdx.x * 128, nn0 = blockIdx.y * 64;
    int tid = threadIdx.x, w = tid >> 6, l = tid & 63;
    int lr = l & 15, lg = l >> 4;
    __shared__ __hip_bfloat16 bs[2][64 * 128];  // 32 KB total

    int srow = w * 16 + (l >> 4);
    int sslot = l & 15;

#define GSTAGE(c) do { \
        _Pragma("unroll") \
        for (int i_ = 0; i_ < 4; ++i_) { \
            int row_ = srow + i_ * 4; \
            gload16(Bt + (size_t)(nn0 + row_) * 512 + (c) * 128 + ((sslot ^ (row_ & 15)) << 3), \
                    &bs[(c) & 1][(w * 16 + i_ * 4) * 128]); \
        } } while (0)

    GSTAGE(0);

    // ---- transient LN-stat prologue (MODE 0): wave w covers rows w*32..+31 ----
    float rstd_reg = 0.f, mr_reg = 0.f;
    if constexpr (MODE == 0) {
#pragma unroll 4
        for (int i = 0; i < 32; ++i) {
            bf16x8 u = *reinterpret_cast<const bf16x8*>(
                A + (size_t)(m0 + w * 32 + i) * 512 + l * 8);
            float s = 0.f, sq = 0.f;
#pragma unroll
            for (int j = 0; j < 8; ++j) { float a = (float)u[j]; s += a; sq = fmaf(a, a, sq); }
#pragma unroll
            for (int o = 32; o >= 1; o >>= 1) { s += __shfl_xor(s, o); sq += __shfl_xor(sq, o); }
            float mean = s * (1.0f / 512.0f);
            float var  = sq * (1.0f / 512.0f) - mean * mean;
            float rstd = rsqrtf(var + 1e-5f);
            if ((l & 31) == i) { rstd_reg = rstd; mr_reg = mean * rstd; }
        }
    }

    asm volatile("s_waitcnt vmcnt(0)" ::: "memory");
    __builtin_amdgcn_s_barrier();
    __builtin_amdgcn_sched_barrier(0);

    f32x4 acc0[4] = {}, acc1[4] = {};
    const __hip_bfloat16* ap0 = A + (size_t)(m0 + w * 32 + lr) * 512 + lg * 8;
    const __hip_bfloat16* ap1 = ap0 + 16 * 512;
#pragma unroll
    for (int c = 0; c < 4; ++c) {
        if (c < 3) GSTAGE(c + 1);
        const __hip_bfloat16* bc = &bs[c & 1][0];
#pragma unroll
        for (int kk = 0; kk < 4; ++kk) {
            bf16x8 a0 = *reinterpret_cast<const bf16x8*>(ap0 + c * 128 + kk * 32);
            bf16x8 a1 = *reinterpret_cast<const bf16x8*>(ap1 + c * 128 + kk * 32);
#pragma unroll
            for (int g = 0; g < 4; ++g) {
                int row = g * 16 + lr;
                bf16x8 bf = *reinterpret_cast<const bf16x8*>(
                    bc + row * 128 + (((kk * 4 + lg) ^ (row & 15)) << 3));
                acc0[g] = MFMA16(a0, bf, acc0[g]);
                acc1[g] = MFMA16(a1, bf, acc1[g]);
            }
        }
        if (c < 3) {
            asm volatile("s_waitcnt vmcnt(0)" ::: "memory");
            __builtin_amdgcn_s_barrier();
            __builtin_amdgcn_sched_barrier(0);
        }
    }
#undef GSTAGE
#pragma unroll
    for (int g = 0; g < 4; ++g) {
        int col = nn0 + g * 16 + lr;
        float bb = bias[col];
        float cc = (MODE == 0) ? csum[col] : 0.f;
#pragma unroll
        for (int r = 0; r < 4; ++r) {
            int row0 = m0 + w * 32 + lg * 4 + r;
            if (MODE == 0) {
                float rs0 = __shfl(rstd_reg, lg * 4 + r);
                float mr0 = __shfl(mr_reg,  lg * 4 + r);
                float rs1 = __shfl(rstd_reg, lg * 4 + r + 16);
                float mr1 = __shfl(mr_reg,  lg * 4 + r + 16);
                float v0 = fmaf(acc0[g][r], rs0, fmaf(-mr0, cc, bb));
                float v1 = fmaf(acc1[g][r], rs1, fmaf(-mr1, cc, bb));
                outb[(size_t)row0 * 512 + col] = f2bf(gelu_f(v0));
                outb[(size_t)(row0 + 16) * 512 + col] = f2bf(gelu_f(v1));
            } else {
                size_t i0 = (size_t)row0 * 512 + col;
                size_t i1 = (size_t)(row0 + 16) * 512 + col;
                outf[i0] = acc0[g][r] + bb + bf2f(resid[i0]);
                outf[i1] = acc1[g][r] + bb + bf2f(resid[i1]);
            }
        }
    }
}

// ---------------------------------------------------------------------------
extern "C" void kernel_launch(void* const* d_in, const int* in_sizes, int n_in,
                              void* d_out, int out_size, void* d_ws, size_t ws_size,
                              hipStream_t stream) {
    const float* x   = (const float*)d_in[0];
    const float* Wv  = (const float*)d_in[1];
    const float* bv  = (const float*)d_in[2];
    const float* phi = (const float*)d_in[3];
    const float* W1  = (const float*)d_in[4];
    const float* b1  = (const float*)d_in[5];
    const float* W2  = (const float*)d_in[6];
    const float* b2  = (const float*)d_in[7];
    float* out = (float*)d_out;

    char* ws = (char*)d_ws;
    __hip_bfloat16* worth_t = (__hip_bfloat16*)(ws + 0);          // 64 KB
    __hip_bfloat16* wvt     = (__hip_bfloat16*)(ws + 65536);      // 64 KB
    __hip_bfloat16* w1t     = (__hip_bfloat16*)(ws + 131072);     // 512 KB
    __hip_bfloat16* w2t     = (__hip_bfloat16*)(ws + 655360);     // 512 KB
    float*          csum1   = (float*)(ws + 1179648);             // 2 KB
    __hip_bfloat16* xn      = (__hip_bfloat16*)(ws + 1312768);    // 16 MB
    __hip_bfloat16* vt      = (__hip_bfloat16*)(ws + 18089984);   // 16 MB
    __hip_bfloat16* res     = (__hip_bfloat16*)(ws + 34867200);   // 16 MB
    __hip_bfloat16* y1      = (__hip_bfloat16*)(ws + 51644416);   // 16 MB
    __hip_bfloat16* xb      = (__hip_bfloat16*)(ws + 68421632);   // 16 MB

    k_prep<<<dim3(4240), dim3(256), 0, stream>>>(phi, Wv, W1, W2, x,
                                                 worth_t, wvt, w1t, w2t, csum1, xn, xb);
    k_proj<<<dim3(256, 8), dim3(256), 0, stream>>>(xn, wvt, bv, vt);
    k_attn<<<dim3(8, 4, 16), dim3(512), 0, stream>>>(xn, worth_t, vt, xb, res);
    k_gemm<0><<<dim3(128, 8), dim3(256), 0, stream>>>(res, w1t, b1, nullptr, csum1, y1, nullptr);
    k_gemm<1><<<dim3(128, 8), dim3(256), 0, stream>>>(y1, w2t, b2, res, nullptr, nullptr, out);
}